// Round 1
// baseline (273.418 us; speedup 1.0000x reference)
//
#include <hip/hip_runtime.h>

// Problem constants (fixed by the reference)
constexpr int L    = 8192;   // vector_length (rows of output, reduction dim of pass1)
constexpr int B    = 4096;   // batch (columns)
constexpr int RANK = 8;

// Pass-1 tiling: grid = CB col-blocks x NCHUNK l-chunks
constexpr int CB      = 4;            // column blocks of 1024 cols (256 thr x float4)
constexpr int NCHUNK  = 64;           // l-chunks
constexpr int LPC     = L / NCHUNK;   // 128 l-values per chunk
constexpr int COLS_PB = 1024;

// Pass-2 tiling
constexpr int LPB = 32;               // l-rows per block

// ---------------------------------------------------------------------------
// pass1: partial T: part[lc][r][b] = sum_{l in chunk lc} V[r][l] * in[l][b]
// ---------------------------------------------------------------------------
__global__ __launch_bounds__(256) void lr_pass1(const float* __restrict__ in,
                                                const float* __restrict__ V,
                                                float* __restrict__ part) {
    const int cb  = blockIdx.x % CB;
    const int lc  = blockIdx.x / CB;
    const int col = cb * COLS_PB + threadIdx.x * 4;
    const int l0  = lc * LPC;

    __shared__ float vs[RANK][LPC];     // 4 KiB
    for (int i = threadIdx.x; i < RANK * LPC; i += 256) {
        const int r  = i / LPC;
        const int ll = i % LPC;
        vs[r][ll] = V[r * L + l0 + ll];
    }
    __syncthreads();

    float4 acc[RANK];
#pragma unroll
    for (int r = 0; r < RANK; ++r) acc[r] = make_float4(0.f, 0.f, 0.f, 0.f);

    const float* base = in + (size_t)l0 * B + col;
    for (int li = 0; li < LPC; ++li) {
        const float4 x = *(const float4*)(base + (size_t)li * B);
#pragma unroll
        for (int r = 0; r < RANK; ++r) {
            const float v = vs[r][li];
            acc[r].x += v * x.x;
            acc[r].y += v * x.y;
            acc[r].z += v * x.z;
            acc[r].w += v * x.w;
        }
    }

    float* p = part + (size_t)lc * (RANK * B);
#pragma unroll
    for (int r = 0; r < RANK; ++r) {
        *(float4*)(p + r * B + col) = acc[r];
    }
}

// ---------------------------------------------------------------------------
// reduce: T[i] = sum_c part[c][i],  i in [0, RANK*B)
// ---------------------------------------------------------------------------
__global__ __launch_bounds__(256) void lr_reduce(const float* __restrict__ part,
                                                 float* __restrict__ T) {
    const int i = blockIdx.x * 256 + threadIdx.x;   // grid sized exactly
    float s = 0.f;
#pragma unroll 8
    for (int c = 0; c < NCHUNK; ++c) s += part[(size_t)c * (RANK * B) + i];
    T[i] = s;
}

// ---------------------------------------------------------------------------
// pass2: out[l][b] = sum_r U[r][l] * T[r][b]
// ---------------------------------------------------------------------------
__global__ __launch_bounds__(256) void lr_pass2(const float* __restrict__ T,
                                                const float* __restrict__ U,
                                                float* __restrict__ out) {
    const int cb  = blockIdx.x % CB;
    const int lb  = blockIdx.x / CB;
    const int col = cb * COLS_PB + threadIdx.x * 4;
    const int l0  = lb * LPB;

    __shared__ float us[RANK][LPB];     // 1 KiB
    if (threadIdx.x < RANK * LPB) {
        const int r  = threadIdx.x / LPB;
        const int ll = threadIdx.x % LPB;
        us[r][ll] = U[r * L + l0 + ll];
    }
    __syncthreads();

    float4 t[RANK];
#pragma unroll
    for (int r = 0; r < RANK; ++r) t[r] = *(const float4*)(T + r * B + col);

    for (int li = 0; li < LPB; ++li) {
        float4 o = make_float4(0.f, 0.f, 0.f, 0.f);
#pragma unroll
        for (int r = 0; r < RANK; ++r) {
            const float u = us[r][li];
            o.x += u * t[r].x;
            o.y += u * t[r].y;
            o.z += u * t[r].z;
            o.w += u * t[r].w;
        }
        *(float4*)(out + (size_t)(l0 + li) * B + col) = o;
    }
}

// ---------------------------------------------------------------------------
extern "C" void kernel_launch(void* const* d_in, const int* in_sizes, int n_in,
                              void* d_out, int out_size, void* d_ws, size_t ws_size,
                              hipStream_t stream) {
    const float* in = (const float*)d_in[0];   // [L, B]
    const float* U  = (const float*)d_in[1];   // [RANK, L]
    const float* V  = (const float*)d_in[2];   // [RANK, L]
    float* out = (float*)d_out;                // [L, B]

    // ws layout: partials (NCHUNK * RANK * B floats = 8 MiB) then T (RANK*B)
    float* part = (float*)d_ws;
    float* T    = part + (size_t)NCHUNK * RANK * B;

    lr_pass1 <<<CB * NCHUNK,        256, 0, stream>>>(in, V, part);
    lr_reduce<<<(RANK * B) / 256,   256, 0, stream>>>(part, T);
    lr_pass2 <<<CB * (L / LPB),     256, 0, stream>>>(T, U, out);
}

// Round 2
// 250.672 us; speedup vs baseline: 1.0907x; 1.0907x over previous
//
#include <hip/hip_runtime.h>

// Problem constants (fixed by the reference)
constexpr int L    = 8192;   // vector_length
constexpr int B    = 4096;   // batch (columns)
constexpr int RANK = 8;

// Pass-1 tiling: grid = CB col-blocks x NCHUNK l-chunks
constexpr int CB      = 4;            // column blocks of 1024 cols (256 thr x float4)
constexpr int NCHUNK  = 128;          // l-chunks  -> 512 blocks = 2 blocks/CU
constexpr int LPC     = L / NCHUNK;   // 64 l-values per chunk
constexpr int COLS_PB = 1024;
constexpr int UNROLL  = 8;

// Pass-2 tiling
constexpr int LPB = 16;               // l-rows per block -> 2048 blocks

// ---------------------------------------------------------------------------
// pass1: partial T: part[lc][r][b] = sum_{l in chunk lc} V[r][l] * in[l][b]
// ---------------------------------------------------------------------------
__global__ __launch_bounds__(256) void lr_pass1(const float* __restrict__ in,
                                                const float* __restrict__ V,
                                                float* __restrict__ part) {
    const int cb  = blockIdx.x % CB;
    const int lc  = blockIdx.x / CB;
    const int col = cb * COLS_PB + threadIdx.x * 4;
    const int l0  = lc * LPC;

    __shared__ float vs[RANK][LPC];     // 2 KiB
    for (int i = threadIdx.x; i < RANK * LPC; i += 256) {
        const int r  = i / LPC;
        const int ll = i % LPC;
        vs[r][ll] = V[r * L + l0 + ll];
    }
    __syncthreads();

    float4 acc[RANK];
#pragma unroll
    for (int r = 0; r < RANK; ++r) acc[r] = make_float4(0.f, 0.f, 0.f, 0.f);

    const float* base = in + (size_t)l0 * B + col;
    for (int li = 0; li < LPC; li += UNROLL) {
        float4 x[UNROLL];
#pragma unroll
        for (int j = 0; j < UNROLL; ++j)
            x[j] = *(const float4*)(base + (size_t)(li + j) * B);
#pragma unroll
        for (int j = 0; j < UNROLL; ++j) {
#pragma unroll
            for (int r = 0; r < RANK; ++r) {
                const float v = vs[r][li + j];
                acc[r].x += v * x[j].x;
                acc[r].y += v * x[j].y;
                acc[r].z += v * x[j].z;
                acc[r].w += v * x[j].w;
            }
        }
    }

    float* p = part + (size_t)lc * (RANK * B);
#pragma unroll
    for (int r = 0; r < RANK; ++r) {
        *(float4*)(p + r * B + col) = acc[r];
    }
}

// ---------------------------------------------------------------------------
// reduce: T[i] = sum_c part[c][i],  i in [0, RANK*B)
// 128 blocks x 256 thr; 128 independent loads/thread -> deep MLP
// ---------------------------------------------------------------------------
__global__ __launch_bounds__(256) void lr_reduce(const float* __restrict__ part,
                                                 float* __restrict__ T) {
    const int i = blockIdx.x * 256 + threadIdx.x;
    float s0 = 0.f, s1 = 0.f, s2 = 0.f, s3 = 0.f;
    float s4 = 0.f, s5 = 0.f, s6 = 0.f, s7 = 0.f;
    for (int c = 0; c < NCHUNK; c += 8) {
        const float* p = part + (size_t)c * (RANK * B) + i;
        s0 += p[0 * (size_t)(RANK * B)];
        s1 += p[1 * (size_t)(RANK * B)];
        s2 += p[2 * (size_t)(RANK * B)];
        s3 += p[3 * (size_t)(RANK * B)];
        s4 += p[4 * (size_t)(RANK * B)];
        s5 += p[5 * (size_t)(RANK * B)];
        s6 += p[6 * (size_t)(RANK * B)];
        s7 += p[7 * (size_t)(RANK * B)];
    }
    T[i] = ((s0 + s1) + (s2 + s3)) + ((s4 + s5) + (s6 + s7));
}

// ---------------------------------------------------------------------------
// pass2: out[l][b] = sum_r U[r][l] * T[r][b]
// ---------------------------------------------------------------------------
__global__ __launch_bounds__(256) void lr_pass2(const float* __restrict__ T,
                                                const float* __restrict__ U,
                                                float* __restrict__ out) {
    const int cb  = blockIdx.x % CB;
    const int lb  = blockIdx.x / CB;
    const int col = cb * COLS_PB + threadIdx.x * 4;
    const int l0  = lb * LPB;

    __shared__ float us[RANK][LPB];     // 512 B
    if (threadIdx.x < RANK * LPB) {
        const int r  = threadIdx.x / LPB;
        const int ll = threadIdx.x % LPB;
        us[r][ll] = U[r * L + l0 + ll];
    }
    __syncthreads();

    float4 t[RANK];
#pragma unroll
    for (int r = 0; r < RANK; ++r) t[r] = *(const float4*)(T + r * B + col);

#pragma unroll
    for (int li = 0; li < LPB; ++li) {
        float4 o = make_float4(0.f, 0.f, 0.f, 0.f);
#pragma unroll
        for (int r = 0; r < RANK; ++r) {
            const float u = us[r][li];
            o.x += u * t[r].x;
            o.y += u * t[r].y;
            o.z += u * t[r].z;
            o.w += u * t[r].w;
        }
        *(float4*)(out + (size_t)(l0 + li) * B + col) = o;
    }
}

// ---------------------------------------------------------------------------
extern "C" void kernel_launch(void* const* d_in, const int* in_sizes, int n_in,
                              void* d_out, int out_size, void* d_ws, size_t ws_size,
                              hipStream_t stream) {
    const float* in = (const float*)d_in[0];   // [L, B]
    const float* U  = (const float*)d_in[1];   // [RANK, L]
    const float* V  = (const float*)d_in[2];   // [RANK, L]
    float* out = (float*)d_out;                // [L, B]

    // ws layout: partials (NCHUNK * RANK * B floats = 16 MiB) then T (RANK*B)
    float* part = (float*)d_ws;
    float* T    = part + (size_t)NCHUNK * RANK * B;

    lr_pass1 <<<CB * NCHUNK,      256, 0, stream>>>(in, V, part);
    lr_reduce<<<(RANK * B) / 256, 256, 0, stream>>>(part, T);
    lr_pass2 <<<CB * (L / LPB),   256, 0, stream>>>(T, U, out);
}